// Round 1
// baseline (132.378 us; speedup 1.0000x reference)
//
#include <hip/hip_runtime.h>

#define HH  480
#define WW  480
#define ZZ  2
#define CC  64
#define CIN 4
#define BN_EPS 1e-3f

// One thread per (c, b, n), c-major so consecutive threads share c and walk n:
//  - coalesced float4 load of feats[b][n][0:4]
//  - coalesced int loads of coords[b][n][0:3]
//  - wave-uniform scalar loads of W[c][*], BN params
//  - coalesced store to out0[b][c][n]
//  - scatter atomicMax (uint-bitwise == float max for vals >= 0) into grid
__global__ __launch_bounds__(256) void pfn_kernel(
    const float* __restrict__ feats,   // [B, N, 4]
    const int*   __restrict__ coords,  // [B, N, 3] (int32)
    const float* __restrict__ W,       // [64, 4]
    const float* __restrict__ gamma,   // [64]
    const float* __restrict__ beta,    // [64]
    const float* __restrict__ rmean,   // [64]
    const float* __restrict__ rvar,    // [64]
    float*       __restrict__ out0,    // [B, 64, N]
    float*       __restrict__ out1,    // [B, Z, 64, H, W] (pre-zeroed)
    int N, int B)
{
    long gid = (long)blockIdx.x * blockDim.x + threadIdx.x;
    long total = (long)CC * B * N;
    if (gid >= total) return;

    int n   = (int)(gid % N);
    int rem = (int)(gid / N);
    int b   = rem % B;
    int c   = rem / B;

    long pt = (long)b * N + n;

    float4 f = *reinterpret_cast<const float4*>(feats + pt * CIN);

    // wave-uniform (all 64 lanes share c)
    float w0 = W[c * CIN + 0];
    float w1 = W[c * CIN + 1];
    float w2 = W[c * CIN + 2];
    float w3 = W[c * CIN + 3];
    float scale = gamma[c] * rsqrtf(rvar[c] + BN_EPS);
    float bias  = beta[c] - rmean[c] * scale;

    float val = f.x * w0 + f.y * w1 + f.z * w2 + f.w * w3;
    val = fmaxf(val * scale + bias, 0.0f);

    // output 0: [B, C, N]
    out0[((long)(b * CC + c)) * N + n] = val;

    // scatter-max into grid: out1[b][z][c][h][w], h=cx, w=cy
    int cx = coords[pt * 3 + 0];
    int cy = coords[pt * 3 + 1];
    int cz = coords[pt * 3 + 2];
    long o1 = ((((long)(b * ZZ + cz)) * CC + c) * HH + cx) * WW + cy;
    atomicMax(reinterpret_cast<unsigned int*>(out1) + o1, __float_as_uint(val));
}

extern "C" void kernel_launch(void* const* d_in, const int* in_sizes, int n_in,
                              void* d_out, int out_size, void* d_ws, size_t ws_size,
                              hipStream_t stream) {
    const float* feats  = (const float*)d_in[0];
    const int*   coords = (const int*)d_in[1];
    const float* W      = (const float*)d_in[2];
    const float* gamma  = (const float*)d_in[3];
    const float* beta   = (const float*)d_in[4];
    const float* rmean  = (const float*)d_in[5];
    const float* rvar   = (const float*)d_in[6];

    const int B = 2;                          // bs * seq = 2 * 1
    const int N = in_sizes[0] / (B * CIN);    // 20000

    float* out0 = (float*)d_out;
    long   out0_sz = (long)B * CC * N;        // 2,560,000
    float* out1 = out0 + out0_sz;             // 58,982,400 floats
    size_t out1_bytes = (size_t)B * ZZ * CC * HH * WW * sizeof(float);

    // grid output must be zero every call (harness poisons once, never restores)
    hipMemsetAsync(out1, 0, out1_bytes, stream);

    long total  = (long)CC * B * N;
    int  blocks = (int)((total + 255) / 256);
    pfn_kernel<<<blocks, 256, 0, stream>>>(feats, coords, W, gamma, beta,
                                           rmean, rvar, out0, out1, N, B);
}

// Round 2
// 62.816 us; speedup vs baseline: 2.1074x; 2.1074x over previous
//
#include <hip/hip_runtime.h>

#define HH  480
#define WW  480
#define ZZ  2
#define CC  64
#define CIN 4
#define BN_EPS 1e-3f
#define CTILE 16   // channels per pass-B block; LDS = 16*480*4 = 30 KB -> 5 blocks/CU

// ---------------- Pass A: per-point compute + out0 + voxel linked lists ------
__global__ __launch_bounds__(256) void pfn_pass_a(
    const float* __restrict__ feats,   // [B, N, 4]
    const int*   __restrict__ coords,  // [B, N, 3]
    const float* __restrict__ W,       // [64, 4]
    const float* __restrict__ gamma,
    const float* __restrict__ beta,
    const float* __restrict__ rmean,
    const float* __restrict__ rvar,
    float* __restrict__ out0,          // [B, 64, N]
    int*   __restrict__ head,          // [B*Z*H*W], pre-set to -1
    int*   __restrict__ nxt,           // [B*N]
    int N, int B)
{
    int gid = blockIdx.x * blockDim.x + threadIdx.x;
    int total = B * N;
    if (gid >= total) return;
    int n = gid % N;
    int b = gid / N;

    float4 f = *reinterpret_cast<const float4*>(feats + (long)gid * CIN);

    #pragma unroll 8
    for (int c = 0; c < CC; ++c) {
        float scale = gamma[c] * rsqrtf(rvar[c] + BN_EPS);
        float bias  = beta[c] - rmean[c] * scale;
        float v = f.x * W[c*4+0] + f.y * W[c*4+1] + f.z * W[c*4+2] + f.w * W[c*4+3];
        v = fmaxf(v * scale + bias, 0.0f);
        out0[((long)(b * CC + c)) * N + n] = v;   // coalesced across lanes (n)
    }

    int cx = coords[(long)gid*3 + 0];
    int cy = coords[(long)gid*3 + 1];
    int cz = coords[(long)gid*3 + 2];
    int vox = ((b * ZZ + cz) * HH + cx) * WW + cy;
    nxt[gid] = atomicExch(&head[vox], gid);       // order-free: max is commutative
}

// ---------------- Pass B: gather per (b,z,h,ct), stream grid out once --------
__global__ __launch_bounds__(256) void pfn_pass_b(
    const float* __restrict__ feats,
    const float* __restrict__ W,
    const float* __restrict__ gamma,
    const float* __restrict__ beta,
    const float* __restrict__ rmean,
    const float* __restrict__ rvar,
    const int*   __restrict__ head,
    const int*   __restrict__ nxt,
    float* __restrict__ out1,          // [B, Z, 64, H, W]
    int N, int B)
{
    // bid = ((b*ZZ + z)*HH + h) * (CC/CTILE) + ct
    int bid = blockIdx.x;
    const int ntile = CC / CTILE;
    int ct  = bid % ntile;
    int rem = bid / ntile;
    int h   = rem % HH;
    int z   = (rem / HH) % ZZ;
    int b   = rem / (HH * ZZ);
    const int c0 = ct * CTILE;

    __shared__ float tile[CTILE][WW];             // 30 KB
    float4* t4 = reinterpret_cast<float4*>(&tile[0][0]);
    const int n4 = CTILE * WW / 4;                // 1920

    for (int i = threadIdx.x; i < n4; i += 256)
        t4[i] = make_float4(0.f, 0.f, 0.f, 0.f);
    __syncthreads();

    // per-ctile BN constants (uniform, tiny)
    float scale[CTILE], bias[CTILE], w0[CTILE], w1[CTILE], w2[CTILE], w3[CTILE];
    #pragma unroll
    for (int j = 0; j < CTILE; ++j) {
        int c = c0 + j;
        scale[j] = gamma[c] * rsqrtf(rvar[c] + BN_EPS);
        bias[j]  = beta[c] - rmean[c] * scale[j];
        w0[j] = W[c*4+0]; w1[j] = W[c*4+1]; w2[j] = W[c*4+2]; w3[j] = W[c*4+3];
    }

    const int row_base = ((b * ZZ + z) * HH + h) * WW;
    for (int w = threadIdx.x; w < WW; w += 256) {
        int p = head[row_base + w];
        while (p >= 0) {
            float4 f = *reinterpret_cast<const float4*>(feats + (long)p * CIN);
            #pragma unroll
            for (int j = 0; j < CTILE; ++j) {
                float v = f.x * w0[j] + f.y * w1[j] + f.z * w2[j] + f.w * w3[j];
                v = fmaxf(v * scale[j] + bias[j], 0.0f);
                tile[j][w] = fmaxf(tile[j][w], v);
            }
            p = nxt[p];
        }
    }
    __syncthreads();

    // stream out: 16 contiguous rows of 480 floats, float4-vectorized
    const long plane = (long)HH * WW;
    const long base  = (((long)(b * ZZ + z)) * CC + c0) * plane + (long)h * WW;
    const int w4row = WW / 4;                     // 120
    for (int i = threadIdx.x; i < n4; i += 256) {
        int c  = i / w4row;
        int w4 = i % w4row;
        *reinterpret_cast<float4*>(out1 + base + (long)c * plane + (long)w4 * 4) = t4[i];
    }
}

// ---------------- Fallback (round-1 path) if ws too small --------------------
__global__ __launch_bounds__(256) void pfn_fallback(
    const float* __restrict__ feats, const int* __restrict__ coords,
    const float* __restrict__ W, const float* __restrict__ gamma,
    const float* __restrict__ beta, const float* __restrict__ rmean,
    const float* __restrict__ rvar, float* __restrict__ out0,
    float* __restrict__ out1, int N, int B)
{
    long gid = (long)blockIdx.x * blockDim.x + threadIdx.x;
    long total = (long)CC * B * N;
    if (gid >= total) return;
    int n = (int)(gid % N); int rem = (int)(gid / N);
    int b = rem % B; int c = rem / B;
    long pt = (long)b * N + n;
    float4 f = *reinterpret_cast<const float4*>(feats + pt * CIN);
    float scale = gamma[c] * rsqrtf(rvar[c] + BN_EPS);
    float bias  = beta[c] - rmean[c] * scale;
    float val = f.x*W[c*4] + f.y*W[c*4+1] + f.z*W[c*4+2] + f.w*W[c*4+3];
    val = fmaxf(val * scale + bias, 0.0f);
    out0[((long)(b * CC + c)) * N + n] = val;
    int cx = coords[pt*3+0], cy = coords[pt*3+1], cz = coords[pt*3+2];
    long o1 = ((((long)(b * ZZ + cz)) * CC + c) * HH + cx) * WW + cy;
    atomicMax(reinterpret_cast<unsigned int*>(out1) + o1, __float_as_uint(val));
}

extern "C" void kernel_launch(void* const* d_in, const int* in_sizes, int n_in,
                              void* d_out, int out_size, void* d_ws, size_t ws_size,
                              hipStream_t stream) {
    const float* feats  = (const float*)d_in[0];
    const int*   coords = (const int*)d_in[1];
    const float* W      = (const float*)d_in[2];
    const float* gamma  = (const float*)d_in[3];
    const float* beta   = (const float*)d_in[4];
    const float* rmean  = (const float*)d_in[5];
    const float* rvar   = (const float*)d_in[6];

    const int B = 2;
    const int N = in_sizes[0] / (B * CIN);        // 20000

    float* out0 = (float*)d_out;
    long   out0_sz = (long)B * CC * N;
    float* out1 = out0 + out0_sz;

    const size_t head_elems = (size_t)B * ZZ * HH * WW;      // 921600
    const size_t head_bytes = head_elems * sizeof(int);      // ~3.69 MB
    const size_t next_bytes = (size_t)B * N * sizeof(int);   // 160 KB

    if (ws_size >= head_bytes + next_bytes) {
        int* head = (int*)d_ws;
        int* nxt  = (int*)((char*)d_ws + head_bytes);

        hipMemsetAsync(head, 0xFF, head_bytes, stream);      // head = -1

        int totalA = B * N;
        pfn_pass_a<<<(totalA + 255) / 256, 256, 0, stream>>>(
            feats, coords, W, gamma, beta, rmean, rvar, out0, head, nxt, N, B);

        int blocksB = B * ZZ * HH * (CC / CTILE);            // 7680
        pfn_pass_b<<<blocksB, 256, 0, stream>>>(
            feats, W, gamma, beta, rmean, rvar, head, nxt, out1, N, B);
    } else {
        size_t out1_bytes = (size_t)B * ZZ * CC * HH * WW * sizeof(float);
        hipMemsetAsync(out1, 0, out1_bytes, stream);
        long total = (long)CC * B * N;
        pfn_fallback<<<(int)((total + 255) / 256), 256, 0, stream>>>(
            feats, coords, W, gamma, beta, rmean, rvar, out0, out1, N, B);
    }
}